// Round 2
// baseline (778.223 us; speedup 1.0000x reference)
//
#include <hip/hip_runtime.h>

#define NE 8
#define DD 1024
#define HH 2816
#define TT 16384
#define MAX_TILES (TT / 128 + NE)

typedef __bf16 bf16;
typedef __bf16 bf16x4 __attribute__((ext_vector_type(4)));
typedef __bf16 bf16x8 __attribute__((ext_vector_type(8)));
typedef float f32x4 __attribute__((ext_vector_type(4)));

// ---- workspace layout (bytes) ----
// [hbuf: TT*HH bf16 = 92,274,688][xb: TT*DD bf16 = 33,554,432]
// [w1b: NE*HH*DD bf16 = 46,137,344][w3b: 46,137,344]   total 218,103,808
// w2b aliases w1b (w1b dead after GEMM A; stream-serial so no race).
constexpr size_t HBUF_E = (size_t)TT * HH;
constexpr size_t XN = (size_t)TT * DD;
constexpr size_t WN = (size_t)NE * HH * DD;
constexpr size_t XB_OFF = HBUF_E * 2;
constexpr size_t W1B_OFF = XB_OFF + XN * 2;
constexpr size_t W3B_OFF = W1B_OFF + WN * 2;

__device__ __forceinline__ void gld16(const void* g, void* l) {
  __builtin_amdgcn_global_load_lds(
      (const __attribute__((address_space(1))) void*)g,
      (__attribute__((address_space(3))) void*)l, 16, 0, 0);
}

__device__ __forceinline__ f32x4 mfma16(bf16x8 a, bf16x8 b, f32x4 c) {
  return __builtin_amdgcn_mfma_f32_16x16x32_bf16(a, b, c, 0, 0, 0);
}

// fp32 -> bf16 elementwise convert, 4 elems/thread
__global__ __launch_bounds__(256) void cvt_bf16_k(const float4* __restrict__ in,
                                                  bf16x4* __restrict__ out, int n4) {
  int i = blockIdx.x * 256 + threadIdx.x;
  if (i < n4) {
    float4 v = in[i];
    bf16x4 o;
    o[0] = (bf16)v.x; o[1] = (bf16)v.y; o[2] = (bf16)v.z; o[3] = (bf16)v.w;
    out[i] = o;
  }
}

// Map linear tile id -> (expert, first row, valid rows) from device-side counts.
struct TileInfo { int e, row0, rv; };
__device__ __forceinline__ TileInfo find_tile(const int* __restrict__ cnts, int t) {
  TileInfo ti; ti.e = -1; ti.row0 = 0; ti.rv = 0;
  int off = 0;
#pragma unroll
  for (int i = 0; i < NE; ++i) {
    int c = cnts[i];
    int tl = (c + 127) >> 7;
    if (ti.e < 0) {
      if (t < tl) {
        ti.e = i;
        ti.row0 = off + (t << 7);
        int rv = c - (t << 7);
        ti.rv = rv > 128 ? 128 : rv;
      } else {
        t -= tl;
      }
    }
    off += c;
  }
  return ti;
}

// Kernel A: h = silu(x@w1[e]^T) * (x@w3[e]^T); BM=128, BN=64 (per matrix), BK=32.
__global__ __launch_bounds__(256) void swiglu_gemm_k(
    const bf16* __restrict__ x, const bf16* __restrict__ w1,
    const bf16* __restrict__ w3, const int* __restrict__ cnts,
    bf16* __restrict__ hbuf) {
  constexpr int BK = 32;
  TileInfo ti = find_tile(cnts, blockIdx.x);
  if (ti.e < 0) return;
  const int n0 = blockIdx.y * 64;
  const bf16* w1e = w1 + (size_t)ti.e * HH * DD;
  const bf16* w3e = w3 + (size_t)ti.e * HH * DD;

  __shared__ bf16 lA[128 * BK];
  __shared__ bf16 lB1[64 * BK];
  __shared__ bf16 lB3[64 * BK];

  const int tid = threadIdx.x;
  const int wave = tid >> 6, lane = tid & 63;
  const int wm = wave >> 1, wn = wave & 1;
  const int lr = lane & 15, lk = (lane >> 4) << 3;

  const int rclamp = ti.rv - 1;
  int ar0 = tid >> 2;          // rows 0..63
  int ar1 = (256 + tid) >> 2;  // rows 64..127
  if (ar0 > rclamp) ar0 = rclamp;
  if (ar1 > rclamp) ar1 = rclamp;
  const int ac = (tid & 3) << 3;
  const int brow = tid >> 2;

  const bf16* xb = x + (size_t)ti.row0 * DD;

  f32x4 acc1[4][2], acc3[4][2];
#pragma unroll
  for (int i = 0; i < 4; ++i)
#pragma unroll
    for (int j = 0; j < 2; ++j) {
      acc1[i][j] = f32x4{0.f, 0.f, 0.f, 0.f};
      acc3[i][j] = f32x4{0.f, 0.f, 0.f, 0.f};
    }

  for (int k0 = 0; k0 < DD; k0 += BK) {
    gld16(xb + (size_t)ar0 * DD + k0 + ac, &lA[(size_t)tid * 8]);
    gld16(xb + (size_t)ar1 * DD + k0 + ac, &lA[(size_t)(256 + tid) * 8]);
    gld16(w1e + (size_t)(n0 + brow) * DD + k0 + ac, &lB1[(size_t)tid * 8]);
    gld16(w3e + (size_t)(n0 + brow) * DD + k0 + ac, &lB3[(size_t)tid * 8]);
    __syncthreads();

    bf16x8 af[4], b1f[2], b3f[2];
#pragma unroll
    for (int mt = 0; mt < 4; ++mt)
      af[mt] = *(const bf16x8*)&lA[(wm * 64 + mt * 16 + lr) * BK + lk];
#pragma unroll
    for (int nt = 0; nt < 2; ++nt) {
      b1f[nt] = *(const bf16x8*)&lB1[(wn * 32 + nt * 16 + lr) * BK + lk];
      b3f[nt] = *(const bf16x8*)&lB3[(wn * 32 + nt * 16 + lr) * BK + lk];
    }
#pragma unroll
    for (int mt = 0; mt < 4; ++mt)
#pragma unroll
      for (int nt = 0; nt < 2; ++nt) {
        acc1[mt][nt] = mfma16(af[mt], b1f[nt], acc1[mt][nt]);
        acc3[mt][nt] = mfma16(af[mt], b3f[nt], acc3[mt][nt]);
      }
    __syncthreads();
  }

  const int rquad = (lane >> 4) << 2;
#pragma unroll
  for (int mt = 0; mt < 4; ++mt) {
#pragma unroll
    for (int r = 0; r < 4; ++r) {
      int row = wm * 64 + mt * 16 + rquad + r;
      if (row < ti.rv) {
        size_t base = (size_t)(ti.row0 + row) * HH + n0 + wn * 32 + lr;
#pragma unroll
        for (int nt = 0; nt < 2; ++nt) {
          float a = acc1[mt][nt][r];
          float b = acc3[mt][nt][r];
          float s = a / (1.f + __expf(-a));
          hbuf[base + nt * 16] = (bf16)(s * b);
        }
      }
    }
  }
}

// Kernel B: out[m, d] = h @ w2[e]^T; BM=128, BN=128, BK=32. fp32 output.
__global__ __launch_bounds__(256) void down_gemm_k(
    const bf16* __restrict__ hbuf, const bf16* __restrict__ w2,
    const int* __restrict__ cnts, float* __restrict__ out) {
  constexpr int BK = 32;
  TileInfo ti = find_tile(cnts, blockIdx.x);
  if (ti.e < 0) return;
  const int n0 = blockIdx.y * 128;
  const bf16* w2e = w2 + (size_t)ti.e * DD * HH;

  __shared__ bf16 lA[128 * BK];
  __shared__ bf16 lB[128 * BK];

  const int tid = threadIdx.x;
  const int wave = tid >> 6, lane = tid & 63;
  const int wm = wave >> 1, wn = wave & 1;
  const int lr = lane & 15, lk = (lane >> 4) << 3;

  const int rclamp = ti.rv - 1;
  int ar0 = tid >> 2;
  int ar1 = (256 + tid) >> 2;
  const int br0 = tid >> 2;
  const int br1 = (256 + tid) >> 2;
  if (ar0 > rclamp) ar0 = rclamp;
  if (ar1 > rclamp) ar1 = rclamp;
  const int ac = (tid & 3) << 3;

  const bf16* hb = hbuf + (size_t)ti.row0 * HH;

  f32x4 acc[4][4];
#pragma unroll
  for (int i = 0; i < 4; ++i)
#pragma unroll
    for (int j = 0; j < 4; ++j) acc[i][j] = f32x4{0.f, 0.f, 0.f, 0.f};

  for (int k0 = 0; k0 < HH; k0 += BK) {
    gld16(hb + (size_t)ar0 * HH + k0 + ac, &lA[(size_t)tid * 8]);
    gld16(hb + (size_t)ar1 * HH + k0 + ac, &lA[(size_t)(256 + tid) * 8]);
    gld16(w2e + (size_t)(n0 + br0) * HH + k0 + ac, &lB[(size_t)tid * 8]);
    gld16(w2e + (size_t)(n0 + br1) * HH + k0 + ac, &lB[(size_t)(256 + tid) * 8]);
    __syncthreads();

    bf16x8 af[4], bfm[4];
#pragma unroll
    for (int mt = 0; mt < 4; ++mt)
      af[mt] = *(const bf16x8*)&lA[(wm * 64 + mt * 16 + lr) * BK + lk];
#pragma unroll
    for (int nt = 0; nt < 4; ++nt)
      bfm[nt] = *(const bf16x8*)&lB[(wn * 64 + nt * 16 + lr) * BK + lk];
#pragma unroll
    for (int mt = 0; mt < 4; ++mt)
#pragma unroll
      for (int nt = 0; nt < 4; ++nt)
        acc[mt][nt] = mfma16(af[mt], bfm[nt], acc[mt][nt]);
    __syncthreads();
  }

  const int rquad = (lane >> 4) << 2;
#pragma unroll
  for (int mt = 0; mt < 4; ++mt) {
#pragma unroll
    for (int r = 0; r < 4; ++r) {
      int row = wm * 64 + mt * 16 + rquad + r;
      if (row < ti.rv) {
        size_t base = (size_t)(ti.row0 + row) * DD + n0 + wn * 64 + lr;
#pragma unroll
        for (int nt = 0; nt < 4; ++nt) out[base + nt * 16] = acc[mt][nt][r];
      }
    }
  }
}

extern "C" void kernel_launch(void* const* d_in, const int* in_sizes, int n_in,
                              void* d_out, int out_size, void* d_ws, size_t ws_size,
                              hipStream_t stream) {
  const float* x = (const float*)d_in[0];
  const float* w1 = (const float*)d_in[1];
  const float* w2 = (const float*)d_in[2];
  const float* w3 = (const float*)d_in[3];
  const int* cnts = (const int*)d_in[4];
  float* out = (float*)d_out;

  char* ws = (char*)d_ws;
  bf16* hbuf = (bf16*)ws;
  bf16* xb = (bf16*)(ws + XB_OFF);
  bf16* w1b = (bf16*)(ws + W1B_OFF);
  bf16* w3b = (bf16*)(ws + W3B_OFF);
  bf16* w2b = w1b;  // alias: w1b dead after GEMM A, stream-serial

  // zero output (padding rows must be 0); fp32 => 4 bytes/elem
  hipMemsetAsync(d_out, 0, (size_t)out_size * sizeof(float), stream);

  // fp32 -> bf16 converts
  cvt_bf16_k<<<(int)(XN / 4 / 256), 256, 0, stream>>>((const float4*)x, (bf16x4*)xb, (int)(XN / 4));
  cvt_bf16_k<<<(int)(WN / 4 / 256), 256, 0, stream>>>((const float4*)w1, (bf16x4*)w1b, (int)(WN / 4));
  cvt_bf16_k<<<(int)(WN / 4 / 256), 256, 0, stream>>>((const float4*)w3, (bf16x4*)w3b, (int)(WN / 4));

  dim3 gA(MAX_TILES, HH / 64);
  swiglu_gemm_k<<<gA, 256, 0, stream>>>(xb, w1b, w3b, cnts, hbuf);

  cvt_bf16_k<<<(int)(WN / 4 / 256), 256, 0, stream>>>((const float4*)w2, (bf16x4*)w2b, (int)(WN / 4));

  dim3 gB(MAX_TILES, DD / 128);
  down_gemm_k<<<gB, 256, 0, stream>>>(hbuf, w2b, cnts, out);
}